// Round 1
// baseline (6048.223 us; speedup 1.0000x reference)
//
#include <hip/hip_runtime.h>

#define DM 512
#define DI 1024
#define LSEQ 263
#define NTOK 526
#define NLAYER 32
#define DTR 32
#define DSTATE 16

typedef __attribute__((ext_vector_type(8))) short bf16x8;
typedef __attribute__((ext_vector_type(4))) float f32x4;

__device__ __forceinline__ short f2bf(float f) {
  unsigned u = __float_as_uint(f);
  unsigned r = u + 0x7FFFu + ((u >> 16) & 1u);
  return (short)(r >> 16);
}
__device__ __forceinline__ float silu_f(float v) { return v / (1.f + __expf(-v)); }
__device__ __forceinline__ float softplus_f(float x) {
  return fmaxf(x, 0.f) + log1pf(__expf(-fabsf(x)));
}

// C[M,N] = A[M,K] @ B[N,K]^T (+bias). remap=1: output row r -> (r>>8)*263 + (r&255).
__global__ __launch_bounds__(256) void gemm_bf16(
    const float* __restrict__ A, const float* __restrict__ Bw,
    float* __restrict__ C, const float* __restrict__ bias,
    int M, int N, int K, int remap)
{
  __shared__ short As[64][40];
  __shared__ short Bs[64][40];
  const int tid = threadIdx.x;
  const int lane = tid & 63;
  const int w = tid >> 6;
  const int wm = (w >> 1) * 32, wn = (w & 1) * 32;
  const int m0 = blockIdx.y * 64, n0 = blockIdx.x * 64;
  const int lrow = tid >> 2, lpart = tid & 3;

  f32x4 acc[2][2] = {};

  for (int k0 = 0; k0 < K; k0 += 32) {
    {
      int gr = m0 + lrow;
      float v0=0,v1=0,v2=0,v3=0,v4=0,v5=0,v6=0,v7=0;
      if (gr < M) {
        const float4* p = reinterpret_cast<const float4*>(A + (size_t)gr * K + k0 + lpart * 8);
        float4 u0 = p[0], u1 = p[1];
        v0=u0.x; v1=u0.y; v2=u0.z; v3=u0.w; v4=u1.x; v5=u1.y; v6=u1.z; v7=u1.w;
      }
      bf16x8 o;
      o[0]=f2bf(v0); o[1]=f2bf(v1); o[2]=f2bf(v2); o[3]=f2bf(v3);
      o[4]=f2bf(v4); o[5]=f2bf(v5); o[6]=f2bf(v6); o[7]=f2bf(v7);
      *reinterpret_cast<bf16x8*>(&As[lrow][lpart * 8]) = o;

      const float4* q = reinterpret_cast<const float4*>(Bw + (size_t)(n0 + lrow) * K + k0 + lpart * 8);
      float4 b0 = q[0], b1 = q[1];
      bf16x8 ob;
      ob[0]=f2bf(b0.x); ob[1]=f2bf(b0.y); ob[2]=f2bf(b0.z); ob[3]=f2bf(b0.w);
      ob[4]=f2bf(b1.x); ob[5]=f2bf(b1.y); ob[6]=f2bf(b1.z); ob[7]=f2bf(b1.w);
      *reinterpret_cast<bf16x8*>(&Bs[lrow][lpart * 8]) = ob;
    }
    __syncthreads();
    bf16x8 a0 = *reinterpret_cast<const bf16x8*>(&As[wm + (lane & 15)][(lane >> 4) * 8]);
    bf16x8 a1 = *reinterpret_cast<const bf16x8*>(&As[wm + 16 + (lane & 15)][(lane >> 4) * 8]);
    bf16x8 bb0 = *reinterpret_cast<const bf16x8*>(&Bs[wn + (lane & 15)][(lane >> 4) * 8]);
    bf16x8 bb1 = *reinterpret_cast<const bf16x8*>(&Bs[wn + 16 + (lane & 15)][(lane >> 4) * 8]);
    acc[0][0] = __builtin_amdgcn_mfma_f32_16x16x32_bf16(a0, bb0, acc[0][0], 0, 0, 0);
    acc[0][1] = __builtin_amdgcn_mfma_f32_16x16x32_bf16(a0, bb1, acc[0][1], 0, 0, 0);
    acc[1][0] = __builtin_amdgcn_mfma_f32_16x16x32_bf16(a1, bb0, acc[1][0], 0, 0, 0);
    acc[1][1] = __builtin_amdgcn_mfma_f32_16x16x32_bf16(a1, bb1, acc[1][1], 0, 0, 0);
    __syncthreads();
  }

#pragma unroll
  for (int i = 0; i < 2; ++i)
#pragma unroll
    for (int j = 0; j < 2; ++j)
#pragma unroll
      for (int r = 0; r < 4; ++r) {
        int row = m0 + wm + i * 16 + ((lane >> 4) << 2) + r;
        if (row < M) {
          int col = n0 + wn + j * 16 + (lane & 15);
          float v = acc[i][j][r];
          if (bias) v += bias[col];
          int orow = remap ? ((row >> 8) * LSEQ + (row & 255)) : row;
          C[(size_t)orow * N + col] = v;
        }
      }
}

// res += hs; x = LN(res) * w + b. One block per token row of 512.
__global__ __launch_bounds__(256) void addln_kernel(
    const float* __restrict__ hs, float* __restrict__ res, float* __restrict__ x,
    const float* __restrict__ w, const float* __restrict__ b)
{
  const int t = blockIdx.x, tid = threadIdx.x;
  const size_t base = (size_t)t * DM;
  float r0 = res[base + tid] + hs[base + tid];
  float r1 = res[base + tid + 256] + hs[base + tid + 256];
  res[base + tid] = r0; res[base + tid + 256] = r1;
  float s = r0 + r1, ss = r0 * r0 + r1 * r1;
#pragma unroll
  for (int o = 1; o < 64; o <<= 1) { s += __shfl_xor(s, o); ss += __shfl_xor(ss, o); }
  __shared__ float sb[4], ssb[4];
  if ((tid & 63) == 0) { sb[tid >> 6] = s; ssb[tid >> 6] = ss; }
  __syncthreads();
  s = sb[0] + sb[1] + sb[2] + sb[3];
  ss = ssb[0] + ssb[1] + ssb[2] + ssb[3];
  float mean = s * (1.f / DM);
  float var = ss * (1.f / DM) - mean * mean;
  float rstd = rsqrtf(var + 1e-5f);
  x[base + tid] = (r0 - mean) * rstd * w[tid] + b[tid];
  x[base + tid + 256] = (r1 - mean) * rstd * w[tid + 256] + b[tid + 256];
}

__global__ void set_query_kernel(const float* __restrict__ q, float* __restrict__ hs) {
  int i = blockIdx.x * 256 + threadIdx.x;
  if (i >= 2 * 7 * DM) return;
  int b = i / (7 * DM);
  int rrem = i - b * 7 * DM;
  int t = rrem / DM, d = rrem - t * DM;
  hs[((size_t)b * LSEQ + 256 + t) * DM + d] = q[t * DM + d];
}

// conv1d + silu -> xc; dbc = xproj @ xc; dt = softplus(dt_w @ dbc[:32] + dt_b);
// emits dt, dtx=dt*xc, w1=silu(z), w0=D*xc*silu(z), Bm, Cm. 8 tokens per block.
__global__ __launch_bounds__(256) void prep_kernel(
    const float* __restrict__ xz,
    const float* __restrict__ conv_w, const float* __restrict__ conv_b,
    const float* __restrict__ xproj_w,
    const float* __restrict__ dt_w, const float* __restrict__ dt_b,
    const float* __restrict__ Dsk,
    float* __restrict__ dt, float* __restrict__ dtx,
    float* __restrict__ w1o, float* __restrict__ w0o,
    float* __restrict__ Bm, float* __restrict__ Cm)
{
  __shared__ float xcs[8][DI];
  __shared__ float dbc_s[8][64];
  const int tid = threadIdx.x;
  const int b = blockIdx.x / 33;
  const int tb = (blockIdx.x % 33) * 8;
  const size_t xzb = (size_t)b * LSEQ * 2048;
  const int c0 = tid * 4;

  const float4* cwp = reinterpret_cast<const float4*>(conv_w + (size_t)c0 * 4);
  float4 cw0 = cwp[0], cw1 = cwp[1], cw2 = cwp[2], cw3 = cwp[3];
  float4 cb4 = *reinterpret_cast<const float4*>(conv_b + c0);
  float4 D4 = *reinterpret_cast<const float4*>(Dsk + c0);

  for (int tt = 0; tt < 8; ++tt) {
    int t = tb + tt;
    if (t < LSEQ) {
      float4 xr[4];
#pragma unroll
      for (int k = 0; k < 4; ++k) {
        int ts = t - 3 + k;
        if (ts >= 0) xr[k] = *reinterpret_cast<const float4*>(xz + xzb + (size_t)ts * 2048 + c0);
        else xr[k] = make_float4(0.f, 0.f, 0.f, 0.f);
      }
      float xc0v = silu_f(cb4.x + cw0.x * xr[0].x + cw0.y * xr[1].x + cw0.z * xr[2].x + cw0.w * xr[3].x);
      float xc1v = silu_f(cb4.y + cw1.x * xr[0].y + cw1.y * xr[1].y + cw1.z * xr[2].y + cw1.w * xr[3].y);
      float xc2v = silu_f(cb4.z + cw2.x * xr[0].z + cw2.y * xr[1].z + cw2.z * xr[2].z + cw2.w * xr[3].z);
      float xc3v = silu_f(cb4.w + cw3.x * xr[0].w + cw3.y * xr[1].w + cw3.z * xr[2].w + cw3.w * xr[3].w);
      xcs[tt][c0] = xc0v; xcs[tt][c0+1] = xc1v; xcs[tt][c0+2] = xc2v; xcs[tt][c0+3] = xc3v;
      float4 zv = *reinterpret_cast<const float4*>(xz + xzb + (size_t)t * 2048 + DI + c0);
      float w1x = silu_f(zv.x), w1y = silu_f(zv.y), w1z = silu_f(zv.z), w1w = silu_f(zv.w);
      size_t grow = (size_t)b * LSEQ + t;
      *reinterpret_cast<float4*>(w1o + grow * DI + c0) = make_float4(w1x, w1y, w1z, w1w);
      *reinterpret_cast<float4*>(w0o + grow * DI + c0) =
          make_float4(D4.x * xc0v * w1x, D4.y * xc1v * w1y, D4.z * xc2v * w1z, D4.w * xc3v * w1w);
    } else {
      xcs[tt][c0] = 0.f; xcs[tt][c0+1] = 0.f; xcs[tt][c0+2] = 0.f; xcs[tt][c0+3] = 0.f;
    }
  }
  __syncthreads();
  {
    const int n = tid & 63, tg = tid >> 6;
    const float* wrow = xproj_w + (size_t)n * DI;
    float a0 = 0.f, a1 = 0.f;
    for (int c = 0; c < DI; c += 4) {
      float4 wv = *reinterpret_cast<const float4*>(wrow + c);
      float4 xa = *reinterpret_cast<const float4*>(&xcs[tg][c]);
      float4 xb = *reinterpret_cast<const float4*>(&xcs[tg + 4][c]);
      a0 += wv.x * xa.x + wv.y * xa.y + wv.z * xa.z + wv.w * xa.w;
      a1 += wv.x * xb.x + wv.y * xb.y + wv.z * xb.z + wv.w * xb.w;
    }
    dbc_s[tg][n] = a0;
    dbc_s[tg + 4][n] = a1;
  }
  __syncthreads();
  {
    int t = tid >> 5, i = tid & 31;
    if (tb + t < LSEQ) {
      float v = dbc_s[t][DTR + i];
      size_t grow = (size_t)b * LSEQ + tb + t;
      if (i < DSTATE) Bm[grow * DSTATE + i] = v;
      else Cm[grow * DSTATE + (i - DSTATE)] = v;
    }
  }
  float dtbx = dt_b[c0], dtby = dt_b[c0+1], dtbz = dt_b[c0+2], dtbw = dt_b[c0+3];
  for (int tt = 0; tt < 8; ++tt) {
    int t = tb + tt;
    if (t >= LSEQ) continue;
    float vv[4];
#pragma unroll
    for (int j = 0; j < 4; ++j) {
      const float4* wr = reinterpret_cast<const float4*>(dt_w + (size_t)(c0 + j) * DTR);
      float v = 0.f;
#pragma unroll
      for (int r4 = 0; r4 < 8; ++r4) {
        float4 wq = wr[r4];
        float4 dq = *reinterpret_cast<const float4*>(&dbc_s[tt][r4 * 4]);
        v += wq.x * dq.x + wq.y * dq.y + wq.z * dq.z + wq.w * dq.w;
      }
      vv[j] = v;
    }
    float sp0 = softplus_f(vv[0] + dtbx);
    float sp1 = softplus_f(vv[1] + dtby);
    float sp2 = softplus_f(vv[2] + dtbz);
    float sp3 = softplus_f(vv[3] + dtbw);
    size_t grow = (size_t)b * LSEQ + t;
    *reinterpret_cast<float4*>(dt + grow * DI + c0) = make_float4(sp0, sp1, sp2, sp3);
    *reinterpret_cast<float4*>(dtx + grow * DI + c0) =
        make_float4(sp0 * xcs[tt][c0], sp1 * xcs[tt][c0+1], sp2 * xcs[tt][c0+2], sp3 * xcs[tt][c0+3]);
  }
}

// selective scan: 16 lanes per channel (1 state/lane), butterfly C-dot, LDS chunking.
__global__ __launch_bounds__(256) void scan_kernel(
    const float* __restrict__ dt, const float* __restrict__ dtx,
    const float* __restrict__ Bm, const float* __restrict__ Cm,
    const float* __restrict__ w1, const float* __restrict__ w0,
    const float* __restrict__ A_log, float* __restrict__ y)
{
  const int b = blockIdx.x >> 6;
  const int cbk = blockIdx.x & 63;
  const int tid = threadIdx.x;
  const int n = tid & 15, cl = tid >> 4;
  const int c = cbk * 16 + cl;
  const float Av = -__expf(A_log[(size_t)c * DSTATE + n]);
  float h = 0.f;
  __shared__ float sdt[64][16], sdx[64][16], sB[64][16], sC[64][16], sw1[64][16], sw0[64][16], sy[64][16];
  const size_t rb = (size_t)b * LSEQ;
  for (int t0 = 0; t0 < LSEQ; t0 += 64) {
    int tc = LSEQ - t0; if (tc > 64) tc = 64;
    __syncthreads();
    for (int i = tid; i < tc * 16; i += 256) {
      int tl = i >> 4, cc = i & 15;
      size_t g = (rb + t0 + tl) * DI + cbk * 16 + cc;
      sdt[tl][cc] = dt[g]; sdx[tl][cc] = dtx[g];
      sw1[tl][cc] = w1[g]; sw0[tl][cc] = w0[g];
      size_t gb = (rb + t0 + tl) * DSTATE + cc;
      sB[tl][cc] = Bm[gb]; sC[tl][cc] = Cm[gb];
    }
    __syncthreads();
    for (int tl = 0; tl < tc; ++tl) {
      float e = __expf(sdt[tl][cl] * Av);
      float bx = sdx[tl][cl] * sB[tl][n];
      h = fmaf(e, h, bx);
      float p = h * sC[tl][n];
      p += __shfl_xor(p, 1); p += __shfl_xor(p, 2);
      p += __shfl_xor(p, 4); p += __shfl_xor(p, 8);
      if (n == 0) sy[tl][cl] = fmaf(p, sw1[tl][cl], sw0[tl][cl]);
    }
    __syncthreads();
    for (int i = tid; i < tc * 16; i += 256) {
      int tl = i >> 4, cc = i & 15;
      y[(rb + t0 + tl) * DI + cbk * 16 + cc] = sy[tl][cc];
    }
  }
}

__global__ __launch_bounds__(256) void final_ln_kernel(
    const float* __restrict__ hs, const float* __restrict__ res,
    const float* __restrict__ w, const float* __restrict__ b_,
    float* __restrict__ out)
{
  const int blk = blockIdx.x;
  const int bb = blk / 7, q = blk % 7;
  const int tid = threadIdx.x;
  const size_t base = ((size_t)bb * LSEQ + 256 + q) * DM;
  float r0 = hs[base + tid] + res[base + tid];
  float r1 = hs[base + tid + 256] + res[base + tid + 256];
  float s = r0 + r1, ss = r0 * r0 + r1 * r1;
#pragma unroll
  for (int o = 1; o < 64; o <<= 1) { s += __shfl_xor(s, o); ss += __shfl_xor(ss, o); }
  __shared__ float sb[4], ssb[4];
  if ((tid & 63) == 0) { sb[tid >> 6] = s; ssb[tid >> 6] = ss; }
  __syncthreads();
  s = sb[0] + sb[1] + sb[2] + sb[3];
  ss = ssb[0] + ssb[1] + ssb[2] + ssb[3];
  float mean = s * (1.f / DM);
  float var = ss * (1.f / DM) - mean * mean;
  float rstd = rsqrtf(var + 1e-5f);
  out[((size_t)bb * 7 + q) * DM + tid] = (r0 - mean) * rstd * w[tid] + b_[tid];
  out[((size_t)bb * 7 + q) * DM + tid + 256] = (r1 - mean) * rstd * w[tid + 256] + b_[tid + 256];
}

extern "C" void kernel_launch(void* const* d_in, const int* in_sizes, int n_in,
                              void* d_out, int out_size, void* d_ws, size_t ws_size,
                              hipStream_t stream)
{
  (void)in_sizes; (void)n_in; (void)out_size; (void)ws_size;
  const float* hidden  = (const float*)d_in[0];
  const float* proj_w  = (const float*)d_in[1];
  const float* proj_b  = (const float*)d_in[2];
  const float* query   = (const float*)d_in[3];
  const float* ln_w    = (const float*)d_in[4];
  const float* ln_b    = (const float*)d_in[5];
  const float* in_w    = (const float*)d_in[6];
  const float* conv_w  = (const float*)d_in[7];
  const float* conv_b  = (const float*)d_in[8];
  const float* xproj_w = (const float*)d_in[9];
  const float* dt_w    = (const float*)d_in[10];
  const float* dt_b    = (const float*)d_in[11];
  const float* A_log   = (const float*)d_in[12];
  const float* D_skip  = (const float*)d_in[13];
  const float* out_w   = (const float*)d_in[14];
  const float* norm_w  = (const float*)d_in[15];
  const float* norm_b  = (const float*)d_in[16];
  float* out = (float*)d_out;

  float* p = (float*)d_ws;
  float* res  = p; p += (size_t)NTOK * DM;
  float* hsb  = p; p += (size_t)NTOK * DM;
  float* xb   = p; p += (size_t)NTOK * DM;
  float* xzb  = p; p += (size_t)NTOK * 2048;
  float* dtb_ = p; p += (size_t)NTOK * DI;
  float* dtxb = p; p += (size_t)NTOK * DI;
  float* w1b  = p; p += (size_t)NTOK * DI;
  float* w0b  = p; p += (size_t)NTOK * DI;
  float* yb   = p; p += (size_t)NTOK * DI;
  float* Bmb  = p; p += (size_t)NTOK * DSTATE;
  float* Cmb  = p; p += (size_t)NTOK * DSTATE;

  hipMemsetAsync(res, 0, (size_t)NTOK * DM * sizeof(float), stream);

  // front projection (M=512 exact), bias + remap into concat layout; then query rows
  gemm_bf16<<<dim3(DM / 64, 512 / 64), 256, 0, stream>>>(hidden, proj_w, hsb, proj_b, 512, DM, 1408, 1);
  set_query_kernel<<<28, 256, 0, stream>>>(query, hsb);

  for (int l = 0; l < NLAYER; ++l) {
    addln_kernel<<<NTOK, 256, 0, stream>>>(hsb, res, xb, ln_w + (size_t)l * DM, ln_b + (size_t)l * DM);
    gemm_bf16<<<dim3(2048 / 64, (NTOK + 63) / 64), 256, 0, stream>>>(
        xb, in_w + (size_t)l * 2048 * DM, xzb, nullptr, NTOK, 2048, DM, 0);
    prep_kernel<<<66, 256, 0, stream>>>(
        xzb, conv_w + (size_t)l * DI * 4, conv_b + (size_t)l * DI,
        xproj_w + (size_t)l * 64 * DI, dt_w + (size_t)l * DI * DTR,
        dt_b + (size_t)l * DI, D_skip + (size_t)l * DI,
        dtb_, dtxb, w1b, w0b, Bmb, Cmb);
    scan_kernel<<<128, 256, 0, stream>>>(dtb_, dtxb, Bmb, Cmb, w1b, w0b,
                                         A_log + (size_t)l * DI * DSTATE, yb);
    gemm_bf16<<<dim3(DM / 64, (NTOK + 63) / 64), 256, 0, stream>>>(
        yb, out_w + (size_t)l * DM * DI, hsb, nullptr, NTOK, DM, DI, 0);
  }
  final_ln_kernel<<<14, 256, 0, stream>>>(hsb, res, norm_w, norm_b, out);
}

// Round 4
// 4360.987 us; speedup vs baseline: 1.3869x; 1.3869x over previous
//
#include <hip/hip_runtime.h>

#define DM 512
#define DI 1024
#define LSEQ 263
#define NTOK 526
#define NLAYER 32
#define DTR 32
#define DSTATE 16

typedef __attribute__((ext_vector_type(8))) short bf16x8;
typedef __attribute__((ext_vector_type(4))) short bf16x4;
typedef __attribute__((ext_vector_type(4))) float f32x4;

__device__ __forceinline__ short f2bf(float f) {
  unsigned u = __float_as_uint(f);
  unsigned r = u + 0x7FFFu + ((u >> 16) & 1u);
  return (short)(r >> 16);
}
__device__ __forceinline__ float silu_f(float v) { return v / (1.f + __expf(-v)); }
__device__ __forceinline__ float softplus_f(float x) {
  return fmaxf(x, 0.f) + log1pf(__expf(-fabsf(x)));
}

// C[M,N] = A[M,K] @ Bw[N,K]^T
// MODE 0: front proj  -> C[remap(row)] = acc + bias(x0)
// MODE 1: in_proj     -> A is LN'd per-row on the fly (K==512; x0=ln_w, x1=ln_b)
// MODE 2: out_proj    -> C[row] += acc  (residual accumulate in place)
template<int BM, int BN, int AM, int AN, int MODE>
__global__ __launch_bounds__(256) void gemm_k(
    const float* __restrict__ A, const float* __restrict__ Bw,
    float* __restrict__ C, const float* __restrict__ x0,
    const float* __restrict__ x1, int M, int N, int K)
{
  constexpr int WC = BN / (AN * 16);
  constexpr int TPRA = 256 / BM, EPA = 32 / TPRA;  // threads per A-row, elems per thread
  constexpr int TPRB = 256 / BN, EPB = 32 / TPRB;
  __shared__ short As[BM][40];
  __shared__ short Bs[BN][40];
  __shared__ float mu_s[BM], rs_s[BM];
  const int tid = threadIdx.x;
  const int lane = tid & 63;
  const int w = tid >> 6;
  const int wm = (w / WC) * (AM * 16), wn = (w % WC) * (AN * 16);
  const int m0 = blockIdx.y * BM, n0 = blockIdx.x * BN;
  const int arow = tid / TPRA, acol = (tid % TPRA) * EPA;
  const int brow = tid / TPRB, bcol = (tid % TPRB) * EPB;
  const int agr = m0 + arow;
  const size_t abase = (size_t)agr * K + acol;
  const size_t bbase = (size_t)(n0 + brow) * K + bcol;

  if constexpr (MODE == 1) {
    // per-row LN stats; one wave per row, coalesced 2xfloat4 per lane (K==512)
    for (int r = w; r < BM; r += 4) {
      int row = m0 + r;
      float s = 0.f, ss = 0.f;
      if (row < M) {
        const float4* p = reinterpret_cast<const float4*>(A + (size_t)row * 512 + lane * 8);
        float4 v0 = p[0], v1 = p[1];
        s = v0.x + v0.y + v0.z + v0.w + v1.x + v1.y + v1.z + v1.w;
        ss = v0.x*v0.x + v0.y*v0.y + v0.z*v0.z + v0.w*v0.w
           + v1.x*v1.x + v1.y*v1.y + v1.z*v1.z + v1.w*v1.w;
      }
#pragma unroll
      for (int o = 1; o < 64; o <<= 1) { s += __shfl_xor(s, o); ss += __shfl_xor(ss, o); }
      if (lane == 0) {
        float mean = s * (1.f / 512.f);
        float var = ss * (1.f / 512.f) - mean * mean;
        mu_s[r] = mean;
        rs_s[r] = rsqrtf(var + 1e-5f);
      }
    }
    __syncthreads();
  }

  f32x4 acc[AM][AN] = {};
  float4 pa[2], pb[2], pw[2], pl[2];

  auto loadA = [&](int k0) {
    if (agr < M) {
      const float4* p = reinterpret_cast<const float4*>(A + abase + k0);
      pa[0] = p[0];
      if constexpr (EPA == 8) pa[1] = p[1];
    } else {
      pa[0] = make_float4(0.f, 0.f, 0.f, 0.f);
      pa[1] = make_float4(0.f, 0.f, 0.f, 0.f);
    }
    if constexpr (MODE == 1) {
      const float4* pwp = reinterpret_cast<const float4*>(x0 + k0 + acol);
      const float4* plp = reinterpret_cast<const float4*>(x1 + k0 + acol);
      pw[0] = pwp[0]; pw[1] = pwp[1];
      pl[0] = plp[0]; pl[1] = plp[1];
    }
  };
  auto loadB = [&](int k0) {
    const float4* p = reinterpret_cast<const float4*>(Bw + bbase + k0);
    pb[0] = p[0];
    if constexpr (EPB == 8) pb[1] = p[1];
  };
  auto stage = [&]() {
    float va[8];
    va[0]=pa[0].x; va[1]=pa[0].y; va[2]=pa[0].z; va[3]=pa[0].w;
    if constexpr (EPA == 8) { va[4]=pa[1].x; va[5]=pa[1].y; va[6]=pa[1].z; va[7]=pa[1].w; }
    if constexpr (MODE == 1) {
      float mu = mu_s[arow], rs = rs_s[arow];
      float wv[8] = {pw[0].x,pw[0].y,pw[0].z,pw[0].w,pw[1].x,pw[1].y,pw[1].z,pw[1].w};
      float bv[8] = {pl[0].x,pl[0].y,pl[0].z,pl[0].w,pl[1].x,pl[1].y,pl[1].z,pl[1].w};
#pragma unroll
      for (int j = 0; j < EPA; ++j) va[j] = (va[j] - mu) * rs * wv[j] + bv[j];
    }
    if constexpr (EPA == 8) {
      bf16x8 o;
#pragma unroll
      for (int j = 0; j < 8; ++j) o[j] = f2bf(va[j]);
      *reinterpret_cast<bf16x8*>(&As[arow][acol]) = o;
    } else {
      bf16x4 o;
#pragma unroll
      for (int j = 0; j < 4; ++j) o[j] = f2bf(va[j]);
      *reinterpret_cast<bf16x4*>(&As[arow][acol]) = o;
    }
    float vb[8];
    vb[0]=pb[0].x; vb[1]=pb[0].y; vb[2]=pb[0].z; vb[3]=pb[0].w;
    if constexpr (EPB == 8) { vb[4]=pb[1].x; vb[5]=pb[1].y; vb[6]=pb[1].z; vb[7]=pb[1].w; }
    if constexpr (EPB == 8) {
      bf16x8 o;
#pragma unroll
      for (int j = 0; j < 8; ++j) o[j] = f2bf(vb[j]);
      *reinterpret_cast<bf16x8*>(&Bs[brow][bcol]) = o;
    } else {
      bf16x4 o;
#pragma unroll
      for (int j = 0; j < 4; ++j) o[j] = f2bf(vb[j]);
      *reinterpret_cast<bf16x4*>(&Bs[brow][bcol]) = o;
    }
  };

  loadA(0); loadB(0);
  const int nk = K / 32;
  for (int kk = 0; kk < nk; ++kk) {
    stage();
    __syncthreads();
    if (kk + 1 < nk) { loadA((kk + 1) * 32); loadB((kk + 1) * 32); }  // prefetch overlaps MFMA
    bf16x8 af[AM], bfr[AN];
#pragma unroll
    for (int i = 0; i < AM; ++i)
      af[i] = *reinterpret_cast<const bf16x8*>(&As[wm + i * 16 + (lane & 15)][(lane >> 4) * 8]);
#pragma unroll
    for (int j = 0; j < AN; ++j)
      bfr[j] = *reinterpret_cast<const bf16x8*>(&Bs[wn + j * 16 + (lane & 15)][(lane >> 4) * 8]);
#pragma unroll
    for (int i = 0; i < AM; ++i)
#pragma unroll
      for (int j = 0; j < AN; ++j)
        acc[i][j] = __builtin_amdgcn_mfma_f32_16x16x32_bf16(af[i], bfr[j], acc[i][j], 0, 0, 0);
    __syncthreads();
  }

#pragma unroll
  for (int i = 0; i < AM; ++i)
#pragma unroll
    for (int j = 0; j < AN; ++j)
#pragma unroll
      for (int r = 0; r < 4; ++r) {
        int row = m0 + wm + i * 16 + ((lane >> 4) << 2) + r;
        int col = n0 + wn + j * 16 + (lane & 15);
        if (row < M) {
          float v = acc[i][j][r];
          if constexpr (MODE == 0) {
            v += x0[col];
            int orow = ((row >> 8) * LSEQ) + (row & 255);
            C[(size_t)orow * N + col] = v;
          } else if constexpr (MODE == 1) {
            C[(size_t)row * N + col] = v;
          } else {
            C[(size_t)row * N + col] += v;
          }
        }
      }
}

__global__ void set_query_kernel(const float* __restrict__ q, float* __restrict__ res) {
  int i = blockIdx.x * 256 + threadIdx.x;
  if (i >= 2 * 7 * DM) return;
  int b = i / (7 * DM);
  int rrem = i - b * 7 * DM;
  int t = rrem / DM, d = rrem - t * DM;
  res[((size_t)b * LSEQ + 256 + t) * DM + d] = q[t * DM + d];
}

// One block per token. conv+silu -> xc (LDS); dbc via coalesced per-wave GEMV;
// dt via 8-lanes-per-channel coalesced dt_w read; outputs dt, dtx, w1, w0, B, C.
__global__ __launch_bounds__(256) void prep_kernel(
    const float* __restrict__ xz,
    const float* __restrict__ conv_w, const float* __restrict__ conv_b,
    const float* __restrict__ xproj_w,
    const float* __restrict__ dt_w, const float* __restrict__ dt_b,
    const float* __restrict__ Dsk,
    float* __restrict__ dt, float* __restrict__ dtx,
    float* __restrict__ w1o, float* __restrict__ w0o,
    float* __restrict__ Bm, float* __restrict__ Cm)
{
  __shared__ float xcs[DI];
  __shared__ float dbc_s[64];
  __shared__ float sp_s[DI];
  const int blk = blockIdx.x;       // global token row (b*263 + t)
  const int t = blk % LSEQ;
  const int tid = threadIdx.x;
  const int lane = tid & 63;
  const int w = tid >> 6;
  const int c0 = tid * 4;

  // ---- phase A: depthwise conv + silu, z gates ----
  {
    const float4* cwp = reinterpret_cast<const float4*>(conv_w + (size_t)c0 * 4);
    float4 cw0 = cwp[0], cw1 = cwp[1], cw2 = cwp[2], cw3 = cwp[3];
    float4 cb4 = *reinterpret_cast<const float4*>(conv_b + c0);
    float4 D4  = *reinterpret_cast<const float4*>(Dsk + c0);
    float4 xr[4];
#pragma unroll
    for (int k = 0; k < 4; ++k) {
      if (t - 3 + k >= 0)
        xr[k] = *reinterpret_cast<const float4*>(xz + (size_t)(blk - 3 + k) * 2048 + c0);
      else
        xr[k] = make_float4(0.f, 0.f, 0.f, 0.f);
    }
    float xc0 = silu_f(cb4.x + cw0.x*xr[0].x + cw0.y*xr[1].x + cw0.z*xr[2].x + cw0.w*xr[3].x);
    float xc1 = silu_f(cb4.y + cw1.x*xr[0].y + cw1.y*xr[1].y + cw1.z*xr[2].y + cw1.w*xr[3].y);
    float xc2 = silu_f(cb4.z + cw2.x*xr[0].z + cw2.y*xr[1].z + cw2.z*xr[2].z + cw2.w*xr[3].z);
    float xc3 = silu_f(cb4.w + cw3.x*xr[0].w + cw3.y*xr[1].w + cw3.z*xr[2].w + cw3.w*xr[3].w);
    xcs[c0] = xc0; xcs[c0+1] = xc1; xcs[c0+2] = xc2; xcs[c0+3] = xc3;
    float4 zv = *reinterpret_cast<const float4*>(xz + (size_t)blk * 2048 + DI + c0);
    float g0 = silu_f(zv.x), g1 = silu_f(zv.y), g2 = silu_f(zv.z), g3 = silu_f(zv.w);
    *reinterpret_cast<float4*>(w1o + (size_t)blk * DI + c0) = make_float4(g0, g1, g2, g3);
    *reinterpret_cast<float4*>(w0o + (size_t)blk * DI + c0) =
        make_float4(D4.x*xc0*g0, D4.y*xc1*g1, D4.z*xc2*g2, D4.w*xc3*g3);
  }
  __syncthreads();
  // ---- phase B: dbc[n] = xproj_w[n,:] . xc  (wave w owns n = w*16..w*16+15) ----
  {
#pragma unroll 2
    for (int nn = 0; nn < 16; ++nn) {
      int nidx = w * 16 + nn;
      const float4* wr = reinterpret_cast<const float4*>(xproj_w + (size_t)nidx * DI);
      float s = 0.f;
#pragma unroll
      for (int j = 0; j < 4; ++j) {
        float4 wv = wr[j * 64 + lane];                                   // coalesced 1KB/wave
        float4 xv = *reinterpret_cast<const float4*>(&xcs[j * 256 + lane * 4]);
        s += wv.x*xv.x + wv.y*xv.y + wv.z*xv.z + wv.w*xv.w;
      }
#pragma unroll
      for (int o = 1; o < 64; o <<= 1) s += __shfl_xor(s, o);
      if (lane == 0) dbc_s[nidx] = s;
    }
  }
  __syncthreads();
  if (tid < 32) {
    float v = dbc_s[32 + tid];
    if (tid < 16) Bm[(size_t)blk * DSTATE + tid] = v;
    else          Cm[(size_t)blk * DSTATE + (tid - 16)] = v;
  }
  // ---- phase C: dt_raw[c] = dt_w[c,:] . dbc[:32], 8 lanes per channel ----
  {
    const int rp = tid & 7;
    float4 dv = *reinterpret_cast<const float4*>(&dbc_s[rp * 4]);
#pragma unroll 4
    for (int it = 0; it < 32; ++it) {
      int c = it * 32 + (tid >> 3);
      float4 wv = *reinterpret_cast<const float4*>(dt_w + (size_t)c * DTR + rp * 4); // coalesced
      float s = wv.x*dv.x + wv.y*dv.y + wv.z*dv.z + wv.w*dv.w;
      s += __shfl_xor(s, 1); s += __shfl_xor(s, 2); s += __shfl_xor(s, 4);
      if (rp == 0) sp_s[c] = s;
    }
  }
  __syncthreads();
  {
    float4 db4 = *reinterpret_cast<const float4*>(dt_b + c0);
    float sp0 = softplus_f(sp_s[c0+0] + db4.x);
    float sp1 = softplus_f(sp_s[c0+1] + db4.y);
    float sp2 = softplus_f(sp_s[c0+2] + db4.z);
    float sp3 = softplus_f(sp_s[c0+3] + db4.w);
    *reinterpret_cast<float4*>(dt  + (size_t)blk * DI + c0) = make_float4(sp0, sp1, sp2, sp3);
    *reinterpret_cast<float4*>(dtx + (size_t)blk * DI + c0) =
        make_float4(sp0*xcs[c0], sp1*xcs[c0+1], sp2*xcs[c0+2], sp3*xcs[c0+3]);
  }
}

// 256 blocks x 128 threads; 8 channels/block (16 lanes per channel, 1 state/lane).
// 4-step unroll so the four shuffle-reduce trees pipeline.
__global__ __launch_bounds__(128) void scan_kernel(
    const float* __restrict__ dt, const float* __restrict__ dtx,
    const float* __restrict__ Bm, const float* __restrict__ Cm,
    const float* __restrict__ w1, const float* __restrict__ w0,
    const float* __restrict__ A_log, float* __restrict__ y)
{
  const int blk = blockIdx.x;
  const int b = blk >> 7, cg = blk & 127;
  const int tid = threadIdx.x;
  const int n = tid & 15, cl = tid >> 4;  // cl in 0..7
  const int c = cg * 8 + cl;
  const float Av = -__expf(A_log[(size_t)c * DSTATE + n]);
  float h = 0.f;
  __shared__ float sdt[64][8], sdx[64][8], sw1[64][8], sw0[64][8], sy[64][8];
  __shared__ float sB[64][16], sC[64][16];
  const size_t rb = (size_t)b * LSEQ;
  for (int t0 = 0; t0 < LSEQ; t0 += 64) {
    const int tc = (LSEQ - t0 < 64) ? (LSEQ - t0) : 64;
    __syncthreads();
    for (int i = tid; i < tc * 8; i += 128) {
      int tl = i >> 3, cc = i & 7;
      size_t g = (rb + t0 + tl) * DI + cg * 8 + cc;
      sdt[tl][cc] = dt[g]; sdx[tl][cc] = dtx[g];
      sw1[tl][cc] = w1[g]; sw0[tl][cc] = w0[g];
    }
    for (int i = tid; i < tc * 16; i += 128) {
      int tl = i >> 4, cc = i & 15;
      size_t gb = (rb + t0 + tl) * DSTATE + cc;
      sB[tl][cc] = Bm[gb]; sC[tl][cc] = Cm[gb];
    }
    __syncthreads();
    int tl = 0;
    for (; tl + 4 <= tc; tl += 4) {
      float e0 = __expf(sdt[tl+0][cl] * Av);
      float e1 = __expf(sdt[tl+1][cl] * Av);
      float e2 = __expf(sdt[tl+2][cl] * Av);
      float e3 = __expf(sdt[tl+3][cl] * Av);
      float x0_ = sdx[tl+0][cl] * sB[tl+0][n];
      float x1_ = sdx[tl+1][cl] * sB[tl+1][n];
      float x2_ = sdx[tl+2][cl] * sB[tl+2][n];
      float x3_ = sdx[tl+3][cl] * sB[tl+3][n];
      h = fmaf(e0, h, x0_); float p0 = h * sC[tl+0][n];
      h = fmaf(e1, h, x1_); float p1 = h * sC[tl+1][n];
      h = fmaf(e2, h, x2_); float p2 = h * sC[tl+2][n];
      h = fmaf(e3, h, x3_); float p3 = h * sC[tl+3][n];
      p0 += __shfl_xor(p0, 1); p1 += __shfl_xor(p1, 1); p2 += __shfl_xor(p2, 1); p3 += __shfl_xor(p3, 1);
      p0 += __shfl_xor(p0, 2); p1 += __shfl_xor(p1, 2); p2 += __shfl_xor(p2, 2); p3 += __shfl_xor(p3, 2);
      p0 += __shfl_xor(p0, 4); p1 += __shfl_xor(p1, 4); p2 += __shfl_xor(p2, 4); p3 += __shfl_xor(p3, 4);
      p0 += __shfl_xor(p0, 8); p1 += __shfl_xor(p1, 8); p2 += __shfl_xor(p2, 8); p3 += __shfl_xor(p3, 8);
      if (n == 0) {
        sy[tl+0][cl] = fmaf(p0, sw1[tl+0][cl], sw0[tl+0][cl]);
        sy[tl+1][cl] = fmaf(p1, sw1[tl+1][cl], sw0[tl+1][cl]);
        sy[tl+2][cl] = fmaf(p2, sw1[tl+2][cl], sw0[tl+2][cl]);
        sy[tl+3][cl] = fmaf(p3, sw1[tl+3][cl], sw0[tl+3][cl]);
      }
    }
    for (; tl < tc; ++tl) {
      float e = __expf(sdt[tl][cl] * Av);
      float bx = sdx[tl][cl] * sB[tl][n];
      h = fmaf(e, h, bx);
      float p = h * sC[tl][n];
      p += __shfl_xor(p, 1); p += __shfl_xor(p, 2);
      p += __shfl_xor(p, 4); p += __shfl_xor(p, 8);
      if (n == 0) sy[tl][cl] = fmaf(p, sw1[tl][cl], sw0[tl][cl]);
    }
    __syncthreads();
    for (int i = tid; i < tc * 8; i += 128) {
      int tl2 = i >> 3, cc = i & 7;
      y[(rb + t0 + tl2) * DI + cg * 8 + cc] = sy[tl2][cc];
    }
  }
}

__global__ __launch_bounds__(256) void final_ln_kernel(
    const float* __restrict__ res, const float* __restrict__ w,
    const float* __restrict__ b_, float* __restrict__ out)
{
  const int blk = blockIdx.x;
  const int bb = blk / 7, q = blk % 7;
  const int tid = threadIdx.x;
  const size_t base = ((size_t)bb * LSEQ + 256 + q) * DM;
  float r0 = res[base + tid];
  float r1 = res[base + tid + 256];
  float s = r0 + r1, ss = r0 * r0 + r1 * r1;
#pragma unroll
  for (int o = 1; o < 64; o <<= 1) { s += __shfl_xor(s, o); ss += __shfl_xor(ss, o); }
  __shared__ float sb[4], ssb[4];
  if ((tid & 63) == 0) { sb[tid >> 6] = s; ssb[tid >> 6] = ss; }
  __syncthreads();
  s = sb[0] + sb[1] + sb[2] + sb[3];
  ss = ssb[0] + ssb[1] + ssb[2] + ssb[3];
  float mean = s * (1.f / DM);
  float var = ss * (1.f / DM) - mean * mean;
  float rstd = rsqrtf(var + 1e-5f);
  out[((size_t)bb * 7 + q) * DM + tid] = (r0 - mean) * rstd * w[tid] + b_[tid];
  out[((size_t)bb * 7 + q) * DM + tid + 256] = (r1 - mean) * rstd * w[tid + 256] + b_[tid + 256];
}

extern "C" void kernel_launch(void* const* d_in, const int* in_sizes, int n_in,
                              void* d_out, int out_size, void* d_ws, size_t ws_size,
                              hipStream_t stream)
{
  (void)in_sizes; (void)n_in; (void)out_size; (void)ws_size;
  const float* hidden  = (const float*)d_in[0];
  const float* proj_w  = (const float*)d_in[1];
  const float* proj_b  = (const float*)d_in[2];
  const float* query   = (const float*)d_in[3];
  const float* ln_w    = (const float*)d_in[4];
  const float* ln_b    = (const float*)d_in[5];
  const float* in_w    = (const float*)d_in[6];
  const float* conv_w  = (const float*)d_in[7];
  const float* conv_b  = (const float*)d_in[8];
  const float* xproj_w = (const float*)d_in[9];
  const float* dt_w    = (const float*)d_in[10];
  const float* dt_b    = (const float*)d_in[11];
  const float* A_log   = (const float*)d_in[12];
  const float* D_skip  = (const float*)d_in[13];
  const float* out_w   = (const float*)d_in[14];
  const float* norm_w  = (const float*)d_in[15];
  const float* norm_b  = (const float*)d_in[16];
  float* out = (float*)d_out;

  float* p = (float*)d_ws;
  float* res  = p; p += (size_t)NTOK * DM;     // running residual (init = h, += hs each layer)
  float* xzb  = p; p += (size_t)NTOK * 2048;
  float* dtb_ = p; p += (size_t)NTOK * DI;
  float* dtxb = p; p += (size_t)NTOK * DI;
  float* w1b  = p; p += (size_t)NTOK * DI;
  float* w0b  = p; p += (size_t)NTOK * DI;
  float* yb   = p; p += (size_t)NTOK * DI;
  float* Bmb  = p; p += (size_t)NTOK * DSTATE;
  float* Cmb  = p; p += (size_t)NTOK * DSTATE;

  // front projection writes res (bias + remap to concat layout); query rows fill the rest
  gemm_k<64,64,2,2,0><<<dim3(DM / 64, 512 / 64), 256, 0, stream>>>(
      hidden, proj_w, res, proj_b, nullptr, 512, DM, 1408);
  set_query_kernel<<<28, 256, 0, stream>>>(query, res);

  for (int l = 0; l < NLAYER; ++l) {
    gemm_k<64,64,2,2,1><<<dim3(2048 / 64, (NTOK + 63) / 64), 256, 0, stream>>>(
        res, in_w + (size_t)l * 2048 * DM, xzb,
        ln_w + (size_t)l * DM, ln_b + (size_t)l * DM, NTOK, 2048, DM);
    prep_kernel<<<NTOK, 256, 0, stream>>>(
        xzb, conv_w + (size_t)l * DI * 4, conv_b + (size_t)l * DI,
        xproj_w + (size_t)l * 64 * DI, dt_w + (size_t)l * DI * DTR,
        dt_b + (size_t)l * DI, D_skip + (size_t)l * DI,
        dtb_, dtxb, w1b, w0b, Bmb, Cmb);
    scan_kernel<<<256, 128, 0, stream>>>(dtb_, dtxb, Bmb, Cmb, w1b, w0b,
                                         A_log + (size_t)l * DI * DSTATE, yb);
    gemm_k<32,32,1,1,2><<<dim3(DM / 32, (NTOK + 31) / 32), 256, 0, stream>>>(
        yb, out_w + (size_t)l * DM * DI, res, nullptr, nullptr, NTOK, DM, DI);
  }
  final_ln_kernel<<<14, 256, 0, stream>>>(res, norm_w, norm_b, out);
}

// Round 5
// 3763.866 us; speedup vs baseline: 1.6069x; 1.1586x over previous
//
#include <hip/hip_runtime.h>

#define DM 512
#define DI 1024
#define LSEQ 263
#define NTOK 526
#define NLAYER 32
#define DTR 32
#define DSTATE 16

typedef __attribute__((ext_vector_type(8))) short bf16x8;
typedef __attribute__((ext_vector_type(4))) float f32x4;

__device__ __forceinline__ short f2bf(float f) {
  unsigned u = __float_as_uint(f);
  unsigned r = u + 0x7FFFu + ((u >> 16) & 1u);
  return (short)(r >> 16);
}
__device__ __forceinline__ float silu_f(float v) { return v / (1.f + __expf(-v)); }
__device__ __forceinline__ float softplus_f(float x) {
  return fmaxf(x, 0.f) + log1pf(__expf(-fabsf(x)));
}

// async 16B global->LDS (linear dst: wave-uniform base + lane*16)
__device__ __forceinline__ void gll16(const void* g, void* l) {
  __builtin_amdgcn_global_load_lds(
      (const __attribute__((address_space(1))) unsigned int*)g,
      (__attribute__((address_space(3))) unsigned int*)l, 16, 0, 0);
}
#define WAITV(n) asm volatile("s_waitcnt vmcnt(" #n ")" ::: "memory")
#define BAR() __builtin_amdgcn_s_barrier()

// ---------------------------------------------------------------------------
// Packed operand layout: per (row-tile tile of 64, k-chunk of 64):
//   unit u (0..511) = ks*256 + g*64 + l  ->  row = tile*64 + g*16 + (l&15),
//   cols = kc*64 + ks*32 + (l>>4)*8 .. +7   (one bf16x8 = 16 B per unit)
// Fragment ds_read for MFMA 16x16x32: lane reads unit (ks*256 + grp*64 + lane),
// lane-stride 16 B -> conflict-free.
// ---------------------------------------------------------------------------

// generic fp32 [L][Nrows][K] -> packed bf16; grid.x = L*ntn*nkc, 256 thr
__global__ __launch_bounds__(256) void pack_w(
    const float* __restrict__ W, short* __restrict__ P,
    int Nrows, int K, int ntn, int nkc)
{
  const int per = ntn * nkc;
  const int layer = blockIdx.x / per, rem = blockIdx.x % per;
  const int tn = rem / nkc, kc = rem % nkc;
  const float* Wl = W + (size_t)layer * Nrows * K;
  short* Pl = P + (size_t)layer * (size_t)per * 4096;
  const int tid = threadIdx.x;
#pragma unroll
  for (int h = 0; h < 2; ++h) {
    int u = h * 256 + tid;
    int ks = u >> 8, g = (u >> 6) & 3, l = u & 63;
    int n = tn * 64 + g * 16 + (l & 15);
    int k = kc * 64 + ks * 32 + (l >> 4) * 8;
    const float4* src = reinterpret_cast<const float4*>(Wl + (size_t)n * K + k);
    float4 v0 = src[0], v1 = src[1];
    bf16x8 o;
    o[0]=f2bf(v0.x); o[1]=f2bf(v0.y); o[2]=f2bf(v0.z); o[3]=f2bf(v0.w);
    o[4]=f2bf(v1.x); o[5]=f2bf(v1.y); o[6]=f2bf(v1.z); o[7]=f2bf(v1.w);
    *reinterpret_cast<bf16x8*>(&Pl[((size_t)(tn * nkc + kc) * 512 + u) * 8]) = o;
  }
}

// per-layer: LN(res) -> packed bf16 A for in_proj. grid = 9 blocks (row tiles)
__global__ __launch_bounds__(256) void pack_x(
    const float* __restrict__ res, const float* __restrict__ lnw,
    const float* __restrict__ lnb, short* __restrict__ P)
{
  __shared__ float mu_s[64], rs_s[64];
  const int tm = blockIdx.x, tid = threadIdx.x;
  const int lane = tid & 63, w = tid >> 6;
  for (int rr = 0; rr < 16; ++rr) {
    int rl = w * 16 + rr, row = tm * 64 + rl;
    float s = 0.f, ss = 0.f;
    if (row < NTOK) {
      const float4* p = reinterpret_cast<const float4*>(res + (size_t)row * DM + lane * 8);
      float4 a = p[0], b = p[1];
      s = a.x+a.y+a.z+a.w+b.x+b.y+b.z+b.w;
      ss = a.x*a.x+a.y*a.y+a.z*a.z+a.w*a.w + b.x*b.x+b.y*b.y+b.z*b.z+b.w*b.w;
    }
#pragma unroll
    for (int o = 1; o < 64; o <<= 1) { s += __shfl_xor(s, o); ss += __shfl_xor(ss, o); }
    if (lane == 0) {
      float mean = s * (1.f / DM);
      float var = ss * (1.f / DM) - mean * mean;
      mu_s[rl] = mean; rs_s[rl] = rsqrtf(var + 1e-5f);
    }
  }
  __syncthreads();
  for (int kc = 0; kc < 8; ++kc) {
#pragma unroll
    for (int h = 0; h < 2; ++h) {
      int u = h * 256 + tid;
      int ks = u >> 8, g = (u >> 6) & 3, l = u & 63;
      int rl = g * 16 + (l & 15), row = tm * 64 + rl;
      int k = kc * 64 + ks * 32 + (l >> 4) * 8;
      float4 v0 = make_float4(0,0,0,0), v1 = v0;
      if (row < NTOK) {
        const float4* p = reinterpret_cast<const float4*>(res + (size_t)row * DM + k);
        v0 = p[0]; v1 = p[1];
      }
      float mu = mu_s[rl], rs = rs_s[rl];
      const float4* pw = reinterpret_cast<const float4*>(lnw + k);
      const float4* pb = reinterpret_cast<const float4*>(lnb + k);
      float4 w0 = pw[0], w1 = pw[1], b0 = pb[0], b1 = pb[1];
      bf16x8 o;
      o[0]=f2bf((v0.x-mu)*rs*w0.x+b0.x); o[1]=f2bf((v0.y-mu)*rs*w0.y+b0.y);
      o[2]=f2bf((v0.z-mu)*rs*w0.z+b0.z); o[3]=f2bf((v0.w-mu)*rs*w0.w+b0.w);
      o[4]=f2bf((v1.x-mu)*rs*w1.x+b1.x); o[5]=f2bf((v1.y-mu)*rs*w1.y+b1.y);
      o[6]=f2bf((v1.z-mu)*rs*w1.z+b1.z); o[7]=f2bf((v1.w-mu)*rs*w1.w+b1.w);
      *reinterpret_cast<bf16x8*>(&P[((size_t)(tm * 8 + kc) * 512 + u) * 8]) = o;
    }
  }
}

// Packed-operand GEMM: C[M,N](fp32) = Apk @ Bpk^T, 64x64 tile, BK=64,
// 3-deep global_load_lds pipeline with counted vmcnt (never 0 until tail).
// MODE 0: front proj -> C[remap(row)] = acc + bias;  1: store;  2: atomicAdd.
template<int NC, int MODE>
__global__ __launch_bounds__(256) void gemm_pk(
    const short* __restrict__ Apk, const short* __restrict__ Bpk,
    float* __restrict__ C, const float* __restrict__ bias,
    int M, int N, int nkc)
{
  __shared__ short As[3][4096];
  __shared__ short Bs[3][4096];
  const int tid = threadIdx.x;
  const int lane = tid & 63, w = tid >> 6;
  const int wr = w >> 1, wc = w & 1;
  const int tn = blockIdx.x, tm = blockIdx.y;
  const int ck0 = blockIdx.z * NC;
  const size_t abase = ((size_t)tm * nkc + ck0) * 512 + tid;
  const size_t bbase = ((size_t)tn * nkc + ck0) * 512 + tid;

  f32x4 acc[2][2] = {};

  auto stage = [&](int t, int s) {
    const short* ga = Apk + (abase + (size_t)t * 512) * 8;
    const short* gb = Bpk + (bbase + (size_t)t * 512) * 8;
    gll16(ga,            &As[s][tid * 8]);
    gll16(ga + 256 * 8,  &As[s][(256 + tid) * 8]);
    gll16(gb,            &Bs[s][tid * 8]);
    gll16(gb + 256 * 8,  &Bs[s][(256 + tid) * 8]);
  };
  auto compute = [&](int s) {
#pragma unroll
    for (int ks = 0; ks < 2; ++ks) {
      bf16x8 a0 = *reinterpret_cast<const bf16x8*>(&As[s][(ks*256 + (wr*2+0)*64 + lane) * 8]);
      bf16x8 a1 = *reinterpret_cast<const bf16x8*>(&As[s][(ks*256 + (wr*2+1)*64 + lane) * 8]);
      bf16x8 b0 = *reinterpret_cast<const bf16x8*>(&Bs[s][(ks*256 + (wc*2+0)*64 + lane) * 8]);
      bf16x8 b1 = *reinterpret_cast<const bf16x8*>(&Bs[s][(ks*256 + (wc*2+1)*64 + lane) * 8]);
      acc[0][0] = __builtin_amdgcn_mfma_f32_16x16x32_bf16(a0, b0, acc[0][0], 0, 0, 0);
      acc[0][1] = __builtin_amdgcn_mfma_f32_16x16x32_bf16(a0, b1, acc[0][1], 0, 0, 0);
      acc[1][0] = __builtin_amdgcn_mfma_f32_16x16x32_bf16(a1, b0, acc[1][0], 0, 0, 0);
      acc[1][1] = __builtin_amdgcn_mfma_f32_16x16x32_bf16(a1, b1, acc[1][1], 0, 0, 0);
    }
  };

  stage(0, 0); stage(1, 1); stage(2, 2);
#pragma unroll 1
  for (int t = 0; t + 3 < NC; ++t) {
    WAITV(8);            // chunk t landed; t+1,t+2 stay in flight
    BAR();
    compute(t % 3);
    BAR();               // all waves done reading slot before overwrite
    stage(t + 3, t % 3);
  }
  WAITV(8); BAR(); compute((NC - 3) % 3);
  WAITV(4); BAR(); compute((NC - 2) % 3);
  WAITV(0); BAR(); compute((NC - 1) % 3);

#pragma unroll
  for (int i = 0; i < 2; ++i)
#pragma unroll
    for (int j = 0; j < 2; ++j)
#pragma unroll
      for (int r = 0; r < 4; ++r) {
        int row = tm * 64 + wr * 32 + i * 16 + ((lane >> 4) << 2) + r;
        int col = tn * 64 + wc * 32 + j * 16 + (lane & 15);
        if (row < M) {
          float v = acc[i][j][r];
          if constexpr (MODE == 0) {
            v += bias[col];
            int orow = ((row >> 8) * LSEQ) + (row & 255);
            C[(size_t)orow * N + col] = v;
          } else if constexpr (MODE == 1) {
            C[(size_t)row * N + col] = v;
          } else {
            atomicAdd(&C[(size_t)row * N + col], v);
          }
        }
      }
}

__global__ void set_query_kernel(const float* __restrict__ q, float* __restrict__ res) {
  int i = blockIdx.x * 256 + threadIdx.x;
  if (i >= 2 * 7 * DM) return;
  int b = i / (7 * DM);
  int rrem = i - b * 7 * DM;
  int t = rrem / DM, d = rrem - t * DM;
  res[((size_t)b * LSEQ + 256 + t) * DM + d] = q[t * DM + d];
}

// One block per token. conv+silu -> xc (LDS); dbc via coalesced per-wave GEMV;
// dt via 8-lanes-per-channel coalesced dt_w read; outputs dt, dtx, w1, w0, B, C.
__global__ __launch_bounds__(256) void prep_kernel(
    const float* __restrict__ xz,
    const float* __restrict__ conv_w, const float* __restrict__ conv_b,
    const float* __restrict__ xproj_w,
    const float* __restrict__ dt_w, const float* __restrict__ dt_b,
    const float* __restrict__ Dsk,
    float* __restrict__ dt, float* __restrict__ dtx,
    float* __restrict__ w1o, float* __restrict__ w0o,
    float* __restrict__ Bm, float* __restrict__ Cm)
{
  __shared__ float xcs[DI];
  __shared__ float dbc_s[64];
  __shared__ float sp_s[DI];
  const int blk = blockIdx.x;
  const int t = blk % LSEQ;
  const int tid = threadIdx.x;
  const int lane = tid & 63;
  const int w = tid >> 6;
  const int c0 = tid * 4;

  {
    const float4* cwp = reinterpret_cast<const float4*>(conv_w + (size_t)c0 * 4);
    float4 cw0 = cwp[0], cw1 = cwp[1], cw2 = cwp[2], cw3 = cwp[3];
    float4 cb4 = *reinterpret_cast<const float4*>(conv_b + c0);
    float4 D4  = *reinterpret_cast<const float4*>(Dsk + c0);
    float4 xr[4];
#pragma unroll
    for (int k = 0; k < 4; ++k) {
      if (t - 3 + k >= 0)
        xr[k] = *reinterpret_cast<const float4*>(xz + (size_t)(blk - 3 + k) * 2048 + c0);
      else
        xr[k] = make_float4(0.f, 0.f, 0.f, 0.f);
    }
    float xc0 = silu_f(cb4.x + cw0.x*xr[0].x + cw0.y*xr[1].x + cw0.z*xr[2].x + cw0.w*xr[3].x);
    float xc1 = silu_f(cb4.y + cw1.x*xr[0].y + cw1.y*xr[1].y + cw1.z*xr[2].y + cw1.w*xr[3].y);
    float xc2 = silu_f(cb4.z + cw2.x*xr[0].z + cw2.y*xr[1].z + cw2.z*xr[2].z + cw2.w*xr[3].z);
    float xc3 = silu_f(cb4.w + cw3.x*xr[0].w + cw3.y*xr[1].w + cw3.z*xr[2].w + cw3.w*xr[3].w);
    xcs[c0] = xc0; xcs[c0+1] = xc1; xcs[c0+2] = xc2; xcs[c0+3] = xc3;
    float4 zv = *reinterpret_cast<const float4*>(xz + (size_t)blk * 2048 + DI + c0);
    float g0 = silu_f(zv.x), g1 = silu_f(zv.y), g2 = silu_f(zv.z), g3 = silu_f(zv.w);
    *reinterpret_cast<float4*>(w1o + (size_t)blk * DI + c0) = make_float4(g0, g1, g2, g3);
    *reinterpret_cast<float4*>(w0o + (size_t)blk * DI + c0) =
        make_float4(D4.x*xc0*g0, D4.y*xc1*g1, D4.z*xc2*g2, D4.w*xc3*g3);
  }
  __syncthreads();
  {
#pragma unroll 2
    for (int nn = 0; nn < 16; ++nn) {
      int nidx = w * 16 + nn;
      const float4* wr = reinterpret_cast<const float4*>(xproj_w + (size_t)nidx * DI);
      float s = 0.f;
#pragma unroll
      for (int j = 0; j < 4; ++j) {
        float4 wv = wr[j * 64 + lane];
        float4 xv = *reinterpret_cast<const float4*>(&xcs[j * 256 + lane * 4]);
        s += wv.x*xv.x + wv.y*xv.y + wv.z*xv.z + wv.w*xv.w;
      }
#pragma unroll
      for (int o = 1; o < 64; o <<= 1) s += __shfl_xor(s, o);
      if (lane == 0) dbc_s[nidx] = s;
    }
  }
  __syncthreads();
  if (tid < 32) {
    float v = dbc_s[32 + tid];
    if (tid < 16) Bm[(size_t)blk * DSTATE + tid] = v;
    else          Cm[(size_t)blk * DSTATE + (tid - 16)] = v;
  }
  {
    const int rp = tid & 7;
    float4 dv = *reinterpret_cast<const float4*>(&dbc_s[rp * 4]);
#pragma unroll 4
    for (int it = 0; it < 32; ++it) {
      int c = it * 32 + (tid >> 3);
      float4 wv = *reinterpret_cast<const float4*>(dt_w + (size_t)c * DTR + rp * 4);
      float s = wv.x*dv.x + wv.y*dv.y + wv.z*dv.z + wv.w*dv.w;
      s += __shfl_xor(s, 1); s += __shfl_xor(s, 2); s += __shfl_xor(s, 4);
      if (rp == 0) sp_s[c] = s;
    }
  }
  __syncthreads();
  {
    float4 db4 = *reinterpret_cast<const float4*>(dt_b + c0);
    float sp0 = softplus_f(sp_s[c0+0] + db4.x);
    float sp1 = softplus_f(sp_s[c0+1] + db4.y);
    float sp2 = softplus_f(sp_s[c0+2] + db4.z);
    float sp3 = softplus_f(sp_s[c0+3] + db4.w);
    *reinterpret_cast<float4*>(dt  + (size_t)blk * DI + c0) = make_float4(sp0, sp1, sp2, sp3);
    *reinterpret_cast<float4*>(dtx + (size_t)blk * DI + c0) =
        make_float4(sp0*xcs[c0], sp1*xcs[c0+1], sp2*xcs[c0+2], sp3*xcs[c0+3]);
  }
}

// selective scan; emits y directly as packed bf16 (A-operand of out_proj).
__global__ __launch_bounds__(128) void scan_kernel(
    const float* __restrict__ dt, const float* __restrict__ dtx,
    const float* __restrict__ Bm, const float* __restrict__ Cm,
    const float* __restrict__ w1, const float* __restrict__ w0,
    const float* __restrict__ A_log, short* __restrict__ ypk)
{
  const int blk = blockIdx.x;
  const int b = blk >> 7, cg = blk & 127;
  const int tid = threadIdx.x;
  const int n = tid & 15, cl = tid >> 4;
  const int c = cg * 8 + cl;
  const float Av = -__expf(A_log[(size_t)c * DSTATE + n]);
  float h = 0.f;
  __shared__ float sdt[64][8], sdx[64][8], sw1[64][8], sw0[64][8], sy[64][8];
  __shared__ float sB[64][16], sC[64][16];
  const size_t rb = (size_t)b * LSEQ;
  // packed-y addressing constants for this block's 8 channels
  const int kc = cg >> 3, ks = (cg >> 2) & 1, cgrp = cg & 3;
  for (int t0 = 0; t0 < LSEQ; t0 += 64) {
    const int tc = (LSEQ - t0 < 64) ? (LSEQ - t0) : 64;
    __syncthreads();
    for (int i = tid; i < tc * 8; i += 128) {
      int tl = i >> 3, cc = i & 7;
      size_t g = (rb + t0 + tl) * DI + cg * 8 + cc;
      sdt[tl][cc] = dt[g]; sdx[tl][cc] = dtx[g];
      sw1[tl][cc] = w1[g]; sw0[tl][cc] = w0[g];
    }
    for (int i = tid; i < tc * 16; i += 128) {
      int tl = i >> 4, cc = i & 15;
      size_t gb = (rb + t0 + tl) * DSTATE + cc;
      sB[tl][cc] = Bm[gb]; sC[tl][cc] = Cm[gb];
    }
    __syncthreads();
    int tl = 0;
    for (; tl + 4 <= tc; tl += 4) {
      float e0 = __expf(sdt[tl+0][cl] * Av);
      float e1 = __expf(sdt[tl+1][cl] * Av);
      float e2 = __expf(sdt[tl+2][cl] * Av);
      float e3 = __expf(sdt[tl+3][cl] * Av);
      float x0_ = sdx[tl+0][cl] * sB[tl+0][n];
      float x1_ = sdx[tl+1][cl] * sB[tl+1][n];
      float x2_ = sdx[tl+2][cl] * sB[tl+2][n];
      float x3_ = sdx[tl+3][cl] * sB[tl+3][n];
      h = fmaf(e0, h, x0_); float p0 = h * sC[tl+0][n];
      h = fmaf(e1, h, x1_); float p1 = h * sC[tl+1][n];
      h = fmaf(e2, h, x2_); float p2 = h * sC[tl+2][n];
      h = fmaf(e3, h, x3_); float p3 = h * sC[tl+3][n];
      p0 += __shfl_xor(p0, 1); p1 += __shfl_xor(p1, 1); p2 += __shfl_xor(p2, 1); p3 += __shfl_xor(p3, 1);
      p0 += __shfl_xor(p0, 2); p1 += __shfl_xor(p1, 2); p2 += __shfl_xor(p2, 2); p3 += __shfl_xor(p3, 2);
      p0 += __shfl_xor(p0, 4); p1 += __shfl_xor(p1, 4); p2 += __shfl_xor(p2, 4); p3 += __shfl_xor(p3, 4);
      p0 += __shfl_xor(p0, 8); p1 += __shfl_xor(p1, 8); p2 += __shfl_xor(p2, 8); p3 += __shfl_xor(p3, 8);
      if (n == 0) {
        sy[tl+0][cl] = fmaf(p0, sw1[tl+0][cl], sw0[tl+0][cl]);
        sy[tl+1][cl] = fmaf(p1, sw1[tl+1][cl], sw0[tl+1][cl]);
        sy[tl+2][cl] = fmaf(p2, sw1[tl+2][cl], sw0[tl+2][cl]);
        sy[tl+3][cl] = fmaf(p3, sw1[tl+3][cl], sw0[tl+3][cl]);
      }
    }
    for (; tl < tc; ++tl) {
      float e = __expf(sdt[tl][cl] * Av);
      float bx = sdx[tl][cl] * sB[tl][n];
      h = fmaf(e, h, bx);
      float p = h * sC[tl][n];
      p += __shfl_xor(p, 1); p += __shfl_xor(p, 2);
      p += __shfl_xor(p, 4); p += __shfl_xor(p, 8);
      if (n == 0) sy[tl][cl] = fmaf(p, sw1[tl][cl], sw0[tl][cl]);
    }
    __syncthreads();
    // packed-bf16 write: one thread per token, 8 channels = one 16B unit
    for (int i2 = tid; i2 < tc; i2 += 128) {
      int r = (int)rb + t0 + i2;            // global token row 0..525
      int tmr = r >> 6, g = (r >> 4) & 3, rl = r & 15;
      bf16x8 o;
#pragma unroll
      for (int cc = 0; cc < 8; ++cc) o[cc] = f2bf(sy[i2][cc]);
      size_t unit = ((size_t)(tmr * 16 + kc) * 512) + ks * 256 + g * 64 + cgrp * 16 + rl;
      *reinterpret_cast<bf16x8*>(&ypk[unit * 8]) = o;
    }
  }
}

__global__ __launch_bounds__(256) void final_ln_kernel(
    const float* __restrict__ res, const float* __restrict__ w,
    const float* __restrict__ b_, float* __restrict__ out)
{
  const int blk = blockIdx.x;
  const int bb = blk / 7, q = blk % 7;
  const int tid = threadIdx.x;
  const size_t base = ((size_t)bb * LSEQ + 256 + q) * DM;
  float r0 = res[base + tid];
  float r1 = res[base + tid + 256];
  float s = r0 + r1, ss = r0 * r0 + r1 * r1;
#pragma unroll
  for (int o = 1; o < 64; o <<= 1) { s += __shfl_xor(s, o); ss += __shfl_xor(ss, o); }
  __shared__ float sb[4], ssb[4];
  if ((tid & 63) == 0) { sb[tid >> 6] = s; ssb[tid >> 6] = ss; }
  __syncthreads();
  s = sb[0] + sb[1] + sb[2] + sb[3];
  ss = ssb[0] + ssb[1] + ssb[2] + ssb[3];
  float mean = s * (1.f / DM);
  float var = ss * (1.f / DM) - mean * mean;
  float rstd = rsqrtf(var + 1e-5f);
  out[((size_t)bb * 7 + q) * DM + tid] = (r0 - mean) * rstd * w[tid] + b_[tid];
  out[((size_t)bb * 7 + q) * DM + tid + 256] = (r1 - mean) * rstd * w[tid + 256] + b_[tid + 256];
}

extern "C" void kernel_launch(void* const* d_in, const int* in_sizes, int n_in,
                              void* d_out, int out_size, void* d_ws, size_t ws_size,
                              hipStream_t stream)
{
  (void)in_sizes; (void)n_in; (void)out_size; (void)ws_size;
  const float* hidden  = (const float*)d_in[0];
  const float* proj_w  = (const float*)d_in[1];
  const float* proj_b  = (const float*)d_in[2];
  const float* query   = (const float*)d_in[3];
  const float* ln_w    = (const float*)d_in[4];
  const float* ln_b    = (const float*)d_in[5];
  const float* in_w    = (const float*)d_in[6];
  const float* conv_w  = (const float*)d_in[7];
  const float* conv_b  = (const float*)d_in[8];
  const float* xproj_w = (const float*)d_in[9];
  const float* dt_w    = (const float*)d_in[10];
  const float* dt_b    = (const float*)d_in[11];
  const float* A_log   = (const float*)d_in[12];
  const float* D_skip  = (const float*)d_in[13];
  const float* out_w   = (const float*)d_in[14];
  const float* norm_w  = (const float*)d_in[15];
  const float* norm_b  = (const float*)d_in[16];
  float* out = (float*)d_out;

  // fp32 workspace
  float* p = (float*)d_ws;
  float* res  = p; p += (size_t)NTOK * DM;
  float* xzb  = p; p += (size_t)NTOK * 2048;
  float* dtb_ = p; p += (size_t)NTOK * DI;
  float* dtxb = p; p += (size_t)NTOK * DI;
  float* w1b  = p; p += (size_t)NTOK * DI;
  float* w0b  = p; p += (size_t)NTOK * DI;
  float* Bmb  = p; p += (size_t)NTOK * DSTATE;
  float* Cmb  = p; p += (size_t)NTOK * DSTATE;
  // bf16 packed workspace (short units of 8)
  short* sp = (short*)p;
  short* inw_pk  = sp; sp += (size_t)NLAYER * 32 * 8 * 4096;   // 32 n-tiles x 8 kc
  short* outw_pk = sp; sp += (size_t)NLAYER * 8 * 16 * 4096;   // 8 n-tiles x 16 kc
  short* projw_pk= sp; sp += (size_t)8 * 22 * 4096;
  short* hid_pk  = sp; sp += (size_t)8 * 22 * 4096;
  short* x_pk    = sp; sp += (size_t)9 * 8 * 4096;
  short* y_pk    = sp; sp += (size_t)9 * 16 * 4096;

  // prologue: pack all fp32 operands to bf16 fragment-major
  pack_w<<<NLAYER * 32 * 8, 256, 0, stream>>>(in_w,  inw_pk,  2048, 512,  32, 8);
  pack_w<<<NLAYER * 8 * 16, 256, 0, stream>>>(out_w, outw_pk, 512,  1024, 8, 16);
  pack_w<<<8 * 22, 256, 0, stream>>>(proj_w, projw_pk, 512, 1408, 8, 22);
  pack_w<<<8 * 22, 256, 0, stream>>>(hidden, hid_pk,   512, 1408, 8, 22);

  // front projection: res = hidden @ proj_w^T + b (remapped rows), query rows
  gemm_pk<22, 0><<<dim3(8, 8, 1), 256, 0, stream>>>(
      hid_pk, projw_pk, res, proj_b, 512, DM, 22);
  set_query_kernel<<<28, 256, 0, stream>>>(query, res);

  for (int l = 0; l < NLAYER; ++l) {
    pack_x<<<9, 256, 0, stream>>>(res, ln_w + (size_t)l * DM, ln_b + (size_t)l * DM, x_pk);
    gemm_pk<8, 1><<<dim3(32, 9, 1), 256, 0, stream>>>(
        x_pk, inw_pk + (size_t)l * 32 * 8 * 4096, xzb, nullptr, NTOK, 2048, 8);
    prep_kernel<<<NTOK, 256, 0, stream>>>(
        xzb, conv_w + (size_t)l * DI * 4, conv_b + (size_t)l * DI,
        xproj_w + (size_t)l * 64 * DI, dt_w + (size_t)l * DI * DTR,
        dt_b + (size_t)l * DI, D_skip + (size_t)l * DI,
        dtb_, dtxb, w1b, w0b, Bmb, Cmb);
    scan_kernel<<<256, 128, 0, stream>>>(dtb_, dtxb, Bmb, Cmb, w1b, w0b,
                                         A_log + (size_t)l * DI * DSTATE, y_pk);
    gemm_pk<4, 2><<<dim3(8, 9, 4), 256, 0, stream>>>(   // K-split x4, atomic +=
        y_pk, outw_pk + (size_t)l * 8 * 16 * 4096, res, nullptr, NTOK, DM, 16);
  }
  final_ln_kernel<<<14, 256, 0, stream>>>(res, norm_w, norm_b, out);
}